// Round 5
// baseline (325.064 us; speedup 1.0000x reference)
//
#include <hip/hip_runtime.h>
#include <math.h>

// InfoNCE: features (4096, 2048, 4) fp32.
// g=1024 groups, ni=4, t=4, n=16 rows/group, c=2048.
// f[g, j, c] = features[g*4 + (j%4), c, j/4]  -> float4 at (b_row, c) holds
// elements of rows {0,4,8,12} + (j%4) for component t = j/4.
//
// R5 design (R4 post-mortem: redundant global reads + tiny per-wave
// in-flight bytes left us latency-bound at ~2.2 TB/s):
//   K1: one block per group (1024 blocks, 256 thr = 4 waves, 4 blocks/CU).
//       Double-buffered LDS tiles (256 c x 4 rows x 16 B = 16 KB) staged via
//       global_load_lds width-16, counted vmcnt(4) (never drained mid-loop),
//       raw s_barrier. Each wave owns a disjoint 34-pair slice of the Gram
//       matrix and reads rows from LDS (broadcast, zero redundancy).
//       ~80 VGPR -> no spill. Epilogue (normalize + InfoNCE) fused in-block.
//   K2: reduce 1024 per-group losses -> out = -sum/48.

#define NGROUP 1024
#define C 2048
#define NPAIR 136        // 16*17/2
#define TC 256           // c-columns per tile
#define NT (C / TC)      // 8 tiles
#define PW 34            // pairs per wave (4 waves * 34 = 136)

__device__ __forceinline__ constexpr int pair_idx(int i, int j) {
    return i * 16 - (i * (i - 1)) / 2 + (j - i);
}

typedef __attribute__((address_space(3))) void lds_void_t;
typedef const __attribute__((address_space(1))) void glob_void_t;

template <int LO, int HI>
__device__ __forceinline__ void run_pairs(const float4* __restrict__ gbase,
                                          const int w, const int lane,
                                          float4 (&tile)[2][4][TC],
                                          float* __restrict__ spair) {
    float acc[HI - LO];
#pragma unroll
    for (int q = 0; q < HI - LO; ++q) acc[q] = 0.f;

    // stage tile t into buffer buf: wave w covers c-quarter w of each row.
    // LDS dest is wave-uniform base (+ lane*16 by HW); global src is per-lane.
    auto STAGE = [&](int buf, int t) {
        const int c0 = t * TC + w * 64 + lane;
#pragma unroll
        for (int L = 0; L < 4; ++L) {
            __builtin_amdgcn_global_load_lds(
                (glob_void_t*)(gbase + (size_t)L * C + c0),
                (lds_void_t*)&tile[buf][L][w * 64],
                16, 0, 0);
        }
    };

    int cur = 0;
    STAGE(0, 0);
    for (int t = 0; t < NT; ++t) {
        if (t + 1 < NT) {
            STAGE(cur ^ 1, t + 1);
            asm volatile("s_waitcnt vmcnt(4)" ::: "memory");  // tile t done, t+1 in flight
        } else {
            asm volatile("s_waitcnt vmcnt(0)" ::: "memory");
        }
        __builtin_amdgcn_s_barrier();          // all waves' slices of tile t visible
        __builtin_amdgcn_sched_barrier(0);

#pragma unroll
        for (int s = 0; s < 4; ++s) {
            const int c = s * 64 + lane;
            const float4 v0 = tile[cur][0][c];
            const float4 v1 = tile[cur][1][c];
            const float4 v2 = tile[cur][2][c];
            const float4 v3 = tile[cur][3][c];
            const float r[16] = { v0.x, v1.x, v2.x, v3.x,
                                  v0.y, v1.y, v2.y, v3.y,
                                  v0.z, v1.z, v2.z, v3.z,
                                  v0.w, v1.w, v2.w, v3.w };
#pragma unroll
            for (int i = 0; i < 16; ++i)
#pragma unroll
                for (int j = i; j < 16; ++j) {
                    const int p = pair_idx(i, j);   // constant after unroll
                    if (p >= LO && p < HI)          // compile-time folded
                        acc[p - LO] = fmaf(r[i], r[j], acc[p - LO]);
                }
        }

        // all ds_reads of buf[cur] consumed before anyone re-stages it
        asm volatile("s_waitcnt lgkmcnt(0)" ::: "memory");
        __builtin_amdgcn_sched_barrier(0);
        __builtin_amdgcn_s_barrier();
        cur ^= 1;
    }

    // wave butterfly: every lane ends with the wave total
#pragma unroll
    for (int q = 0; q < HI - LO; ++q) {
        float x = acc[q];
        x += __shfl_xor(x, 1);
        x += __shfl_xor(x, 2);
        x += __shfl_xor(x, 4);
        x += __shfl_xor(x, 8);
        x += __shfl_xor(x, 16);
        x += __shfl_xor(x, 32);
        if (lane == (q & 63)) spair[LO + q] = x;   // lane-sliced static write
    }
}

__global__ __launch_bounds__(256, 2)
void infonce_group_kernel(const float4* __restrict__ feats,
                          float* __restrict__ gloss) {
    const int g    = blockIdx.x;
    const int tid  = threadIdx.x;
    const int lane = tid & 63;
    const int w    = tid >> 6;

    __shared__ float4 tile[2][4][TC];   // 32 KB double buffer
    __shared__ float spair[NPAIR];
    __shared__ float S[16][17];
    __shared__ float rowloss[16];

    const float4* gbase = feats + (size_t)g * 4 * C;

    if      (w == 0) run_pairs<0,   34>(gbase, w, lane, tile, spair);
    else if (w == 1) run_pairs<34,  68>(gbase, w, lane, tile, spair);
    else if (w == 2) run_pairs<68, 102>(gbase, w, lane, tile, spair);
    else             run_pairs<102,136>(gbase, w, lane, tile, spair);
    __syncthreads();

    if (tid < NPAIR) {
        int i = 0, rem = tid;
        while (rem >= 16 - i) { rem -= 16 - i; ++i; }
        const int j = i + rem;
        const float s = spair[tid];
        S[i][j] = s;
        S[j][i] = s;
    }
    __syncthreads();

    if (tid < 16) {
        const int i = tid;
        const float inv_i = 1.0f / fmaxf(sqrtf(S[i][i]), 1e-12f);
        float logits_row[16];
        float expneg = 0.f;
#pragma unroll
        for (int j = 0; j < 16; ++j) {
            const float inv_j = 1.0f / fmaxf(sqrtf(S[j][j]), 1e-12f);
            const float cosv = S[i][j] * inv_i * inv_j;
            const float lg = cosv / 0.07f;
            logits_row[j] = lg;
            if ((j >> 2) != (i >> 2)) expneg += expf(lg);  // negatives
        }
        float sum = 0.f;
#pragma unroll
        for (int j = 0; j < 16; ++j) {
            if ((j >> 2) == (i >> 2) && j != i) {          // positives
                const float lg = logits_row[j];
                sum += lg - logf(expneg + expf(lg));
            }
        }
        rowloss[i] = sum;
    }
    __syncthreads();

    if (tid == 0) {
        float t = 0.f;
#pragma unroll
        for (int i = 0; i < 16; ++i) t += rowloss[i];
        gloss[g] = t;
    }
}

__global__ void infonce_final_reduce(const float* __restrict__ gloss,
                                     float* __restrict__ out) {
    const int tid = threadIdx.x;
    float s = 0.f;
    for (int i = tid; i < NGROUP; i += 256) s += gloss[i];
    s += __shfl_xor(s, 1);
    s += __shfl_xor(s, 2);
    s += __shfl_xor(s, 4);
    s += __shfl_xor(s, 8);
    s += __shfl_xor(s, 16);
    s += __shfl_xor(s, 32);
    __shared__ float ws[4];
    const int lane = tid & 63, wid = tid >> 6;
    if (lane == 0) ws[wid] = s;
    __syncthreads();
    if (tid == 0) {
        const float t = ws[0] + ws[1] + ws[2] + ws[3];
        out[0] = -t / 48.0f;
    }
}

extern "C" void kernel_launch(void* const* d_in, const int* in_sizes, int n_in,
                              void* d_out, int out_size, void* d_ws, size_t ws_size,
                              hipStream_t stream) {
    const float4* feats = (const float4*)d_in[0];
    float* gloss = (float*)d_ws;   // 1024 floats scratch
    float* out   = (float*)d_out;  // 1 float

    infonce_group_kernel<<<NGROUP, 256, 0, stream>>>(feats, gloss);
    infonce_final_reduce<<<1, 256, 0, stream>>>(gloss, out);
}

// Round 6
// 96.799 us; speedup vs baseline: 3.3581x; 3.3581x over previous
//
#include <hip/hip_runtime.h>
#include <math.h>

// InfoNCE: features (4096, 2048, 4) fp32.
// g=1024 groups, ni=4, t=4, n=16 rows/group, c=2048.
// f[g, j, c] = features[g*4 + (j%4), c, j/4]  -> float4 at (b_row, c) holds
// elements of rows {0,4,8,12} + (j%4) for component t = j/4.
//
// R6 design (R3/R5 post-mortem: every failure was the RA capping at 128 VGPR
// and spilling ~200 MB of scratch):
//   K1: ONE WAVE PER GROUP (grid 1024, block 64, __launch_bounds__(64,1)
//       -> 512-VGPR budget, no spill for ~200 live regs). Direct coalesced
//       float4 loads, manual 3-deep register pipeline (a/b/c sets, 8-12 KB
//       in flight per wave). 136-entry Gram in registers. Cross-lane reduce
//       via 4 DPP row_ror adds + ds_swizzle(xor16) + ds_bpermute(xor32)
//       (272 LDS-pipe ops instead of 816 shuffle ops). Epilogue fused.
//   K2: reduce 1024 per-group losses -> out = -sum/48.

#define NGROUP 1024
#define C 2048           // float4 columns per row
#define NPAIR 136        // 16*17/2
#define NSTEP 32         // 2048 c's / 64 lanes

__device__ __forceinline__ constexpr int pair_idx(int i, int j) {
    return i * 16 - (i * (i - 1)) / 2 + (j - i);
}
__device__ __forceinline__ constexpr int row_of(int p) {
    int i = 0, rem = p;
    while (rem >= 16 - i) { rem -= 16 - i; ++i; }
    return i;
}
__device__ __forceinline__ constexpr int col_of(int p) {
    int i = 0, rem = p;
    while (rem >= 16 - i) { rem -= 16 - i; ++i; }
    return i + rem;
}

template <int CTRL>
__device__ __forceinline__ float dpp_add(float x) {
    union { float f; int i; } a, b;
    a.f = x;
    b.i = __builtin_amdgcn_mov_dpp(a.i, CTRL, 0xf, 0xf, true);
    return a.f + b.f;
}

// full 64-lane sum; every lane ends with the total.
__device__ __forceinline__ float wave_sum64(float x, int lane) {
    x = dpp_add<0x121>(x);   // row_ror:1  (VALU)
    x = dpp_add<0x122>(x);   // row_ror:2
    x = dpp_add<0x124>(x);   // row_ror:4
    x = dpp_add<0x128>(x);   // row_ror:8  -> 16-row sums
    union { float f; int i; } u, v;
    u.f = x;
    v.i = __builtin_amdgcn_ds_swizzle(u.i, 0x401F);             // xor16
    x = u.f + v.f;
    u.f = x;
    v.i = __builtin_amdgcn_ds_bpermute((lane ^ 32) << 2, u.i);  // xor32
    return u.f + v.f;
}

__device__ __forceinline__ void gram_step(const float4 v0, const float4 v1,
                                          const float4 v2, const float4 v3,
                                          float (&acc)[NPAIR]) {
    const float r[16] = { v0.x, v1.x, v2.x, v3.x,
                          v0.y, v1.y, v2.y, v3.y,
                          v0.z, v1.z, v2.z, v3.z,
                          v0.w, v1.w, v2.w, v3.w };
#pragma unroll
    for (int i = 0; i < 16; ++i)
#pragma unroll
        for (int j = i; j < 16; ++j)
            acc[pair_idx(i, j)] = fmaf(r[i], r[j], acc[pair_idx(i, j)]);
}

#define LOADP(X, s) { X##0 = r0[(s) * 64]; X##1 = r1[(s) * 64]; \
                      X##2 = r2[(s) * 64]; X##3 = r3[(s) * 64]; }

__global__ __launch_bounds__(64, 1)
void infonce_group_kernel(const float4* __restrict__ feats,
                          float* __restrict__ gloss) {
    const int g    = blockIdx.x;
    const int lane = threadIdx.x;   // one wave per block

    const float4* r0 = feats + (size_t)g * 4 * C + lane;
    const float4* r1 = r0 + C;
    const float4* r2 = r1 + C;
    const float4* r3 = r2 + C;

    float acc[NPAIR];
#pragma unroll
    for (int p = 0; p < NPAIR; ++p) acc[p] = 0.f;

    float4 a0, a1, a2, a3, b0, b1, b2, b3, c0, c1, c2, c3;

    // 3-deep register pipeline over 32 steps (steps 0..31, 64 c's each)
    LOADP(a, 0)
    LOADP(b, 1)
#pragma unroll 1
    for (int k = 0; k < 10; ++k) {
        const int s = 3 * k;
        LOADP(c, s + 2)
        gram_step(a0, a1, a2, a3, acc);   // step s
        LOADP(a, s + 3)
        gram_step(b0, b1, b2, b3, acc);   // step s+1
        LOADP(b, s + 4)
        gram_step(c0, c1, c2, c3, acc);   // step s+2
    }
    gram_step(a0, a1, a2, a3, acc);       // step 30
    gram_step(b0, b1, b2, b3, acc);       // step 31

    __shared__ float S[16][17];

#pragma unroll
    for (int q = 0; q < NPAIR; ++q) {
        const float tot = wave_sum64(acc[q], lane);
        if (lane == (q & 63)) {           // static owner-lane write
            S[row_of(q)][col_of(q)] = tot;
            S[col_of(q)][row_of(q)] = tot;
        }
    }
    __syncthreads();

    float rloss = 0.f;
    if (lane < 16) {
        const int i = lane;
        const float inv_i = 1.0f / fmaxf(sqrtf(S[i][i]), 1e-12f);
        float lg[16];
        float expneg = 0.f;
#pragma unroll
        for (int j = 0; j < 16; ++j) {
            const float inv_j = 1.0f / fmaxf(sqrtf(S[j][j]), 1e-12f);
            lg[j] = (S[i][j] * inv_i * inv_j) * (1.0f / 0.07f);
            if ((j >> 2) != (i >> 2)) expneg += expf(lg[j]);   // negatives
        }
#pragma unroll
        for (int j = 0; j < 16; ++j) {
            if ((j >> 2) == (i >> 2) && j != i)                // positives
                rloss += lg[j] - logf(expneg + expf(lg[j]));
        }
    }
    // sum lanes 0..15 (others hold 0) via row-local DPP
    rloss = dpp_add<0x121>(rloss);
    rloss = dpp_add<0x122>(rloss);
    rloss = dpp_add<0x124>(rloss);
    rloss = dpp_add<0x128>(rloss);
    if (lane == 0) gloss[g] = rloss;
}

__global__ void infonce_final_reduce(const float* __restrict__ gloss,
                                     float* __restrict__ out) {
    const int tid = threadIdx.x;
    float s = 0.f;
    for (int i = tid; i < NGROUP; i += 256) s += gloss[i];
    s += __shfl_xor(s, 1);
    s += __shfl_xor(s, 2);
    s += __shfl_xor(s, 4);
    s += __shfl_xor(s, 8);
    s += __shfl_xor(s, 16);
    s += __shfl_xor(s, 32);
    __shared__ float ws[4];
    const int lane = tid & 63, wid = tid >> 6;
    if (lane == 0) ws[wid] = s;
    __syncthreads();
    if (tid == 0) {
        const float t = ws[0] + ws[1] + ws[2] + ws[3];
        out[0] = -t / 48.0f;
    }
}

extern "C" void kernel_launch(void* const* d_in, const int* in_sizes, int n_in,
                              void* d_out, int out_size, void* d_ws, size_t ws_size,
                              hipStream_t stream) {
    const float4* feats = (const float4*)d_in[0];
    float* gloss = (float*)d_ws;   // 1024 floats scratch
    float* out   = (float*)d_out;  // 1 float

    infonce_group_kernel<<<NGROUP, 64, 0, stream>>>(feats, gloss);
    infonce_final_reduce<<<1, 256, 0, stream>>>(gloss, out);
}

// Round 8
// 73.665 us; speedup vs baseline: 4.4128x; 1.3140x over previous
//
#include <hip/hip_runtime.h>
#include <math.h>

// InfoNCE: features (4096, 2048, 4) fp32.
// g=1024 groups, ni=4, t=4, n=16 rows/group, c=2048.
// f[g, j, c] = features[g*4 + (j%4), c, j/4]  -> float4 at (b_row, c) holds
// elements of rows {0,4,8,12} + (j%4) for component t = j/4.
//
// R8 = R7 with the reduction bug fixed (R7 post-mortem: per-pair LDS combine
// assumed 4-wave contribution but pairs are wave-exclusive; 12/16 slots
// uninitialized -> inf). Now each wave finishes its pairs entirely in-wave
// via the R6-validated wave_sum64 (DPP row_ror x4 + ds_swizzle xor16 +
// ds_bpermute xor32) and writes S directly.
//   K1: one block (256 thr = 4 waves) per group, 1024 blocks = 4 blocks/CU.
//       Wave w owns a disjoint 34-pair quarter of the Gram matrix, streams
//       the group's FULL c-range (4x L1-amplified reads, 1x HBM traffic).
//       ~90 VGPR -> 4 waves/SIMD resident. Epilogue fused.
//   K2: reduce 1024 per-group losses -> out = -sum/48.

#define NGROUP 1024
#define C 2048           // float4 columns per row
#define NPAIR 136        // 16*17/2
#define NSTEP 32         // 2048 c's / 64 lanes

__device__ __forceinline__ constexpr int pair_idx(int i, int j) {
    return i * 16 - (i * (i - 1)) / 2 + (j - i);
}
__device__ __forceinline__ constexpr int row_of(int p) {
    int i = 0, rem = p;
    while (rem >= 16 - i) { rem -= 16 - i; ++i; }
    return i;
}
__device__ __forceinline__ constexpr int col_of(int p) {
    int i = 0, rem = p;
    while (rem >= 16 - i) { rem -= 16 - i; ++i; }
    return i + rem;
}

template <int CTRL>
__device__ __forceinline__ float dpp_add(float x) {
    union { float f; int i; } a, b;
    a.f = x;
    b.i = __builtin_amdgcn_mov_dpp(a.i, CTRL, 0xf, 0xf, true);
    return a.f + b.f;
}

// sum within each 16-lane row (validated R6: row_ror 1/2/4/8)
__device__ __forceinline__ float rowsum16(float x) {
    x = dpp_add<0x121>(x);
    x = dpp_add<0x122>(x);
    x = dpp_add<0x124>(x);
    x = dpp_add<0x128>(x);
    return x;
}

// full 64-lane sum; every lane ends with the total (validated R6).
__device__ __forceinline__ float wave_sum64(float x, int lane) {
    x = rowsum16(x);
    union { float f; int i; } u, v;
    u.f = x;
    v.i = __builtin_amdgcn_ds_swizzle(u.i, 0x401F);             // xor16
    x = u.f + v.f;
    u.f = x;
    v.i = __builtin_amdgcn_ds_bpermute((lane ^ 32) << 2, u.i);  // xor32
    return u.f + v.f;
}

template <int LO, int HI>
__device__ __forceinline__ void accum_pairs(const float4* __restrict__ r0,
                                            float (*S)[17], const int lane) {
    const float4* r1 = r0 + C;
    const float4* r2 = r1 + C;
    const float4* r3 = r2 + C;

    float acc[HI - LO];
#pragma unroll
    for (int q = 0; q < HI - LO; ++q) acc[q] = 0.f;

#pragma unroll 2
    for (int s = 0; s < NSTEP; ++s) {
        const float4 v0 = r0[s * 64];
        const float4 v1 = r1[s * 64];
        const float4 v2 = r2[s * 64];
        const float4 v3 = r3[s * 64];
        const float r[16] = { v0.x, v1.x, v2.x, v3.x,
                              v0.y, v1.y, v2.y, v3.y,
                              v0.z, v1.z, v2.z, v3.z,
                              v0.w, v1.w, v2.w, v3.w };
#pragma unroll
        for (int i = 0; i < 16; ++i)
#pragma unroll
            for (int j = i; j < 16; ++j) {
                const int p = pair_idx(i, j);   // constant after unroll
                if (p >= LO && p < HI)          // compile-time folded
                    acc[p - LO] = fmaf(r[i], r[j], acc[p - LO]);
            }
    }

    // finish each owned pair entirely in-wave; one owner-lane write to S
#pragma unroll
    for (int q = 0; q < HI - LO; ++q) {
        const float tot = wave_sum64(acc[q], lane);
        const int p = LO + q;
        if (lane == (p & 63)) {                 // static owner-lane write
            S[row_of(p)][col_of(p)] = tot;
            S[col_of(p)][row_of(p)] = tot;
        }
    }
}

__global__ __launch_bounds__(256, 4)
void infonce_group_kernel(const float4* __restrict__ feats,
                          float* __restrict__ gloss) {
    const int g    = blockIdx.x;
    const int tid  = threadIdx.x;
    const int lane = tid & 63;
    const int w    = tid >> 6;

    __shared__ float S[16][17];

    const float4* gbase = feats + (size_t)g * 4 * C + lane;

    if      (w == 0) accum_pairs<0,   34>(gbase, S, lane);
    else if (w == 1) accum_pairs<34,  68>(gbase, S, lane);
    else if (w == 2) accum_pairs<68, 102>(gbase, S, lane);
    else             accum_pairs<102,136>(gbase, S, lane);
    __syncthreads();

    float rloss = 0.f;
    if (tid < 16) {
        const int i = tid;
        const float inv_i = 1.0f / fmaxf(sqrtf(S[i][i]), 1e-12f);
        float lg[16];
        float expneg = 0.f;
#pragma unroll
        for (int j = 0; j < 16; ++j) {
            const float inv_j = 1.0f / fmaxf(sqrtf(S[j][j]), 1e-12f);
            lg[j] = (S[i][j] * inv_i * inv_j) * (1.0f / 0.07f);
            if ((j >> 2) != (i >> 2)) expneg += expf(lg[j]);   // negatives
        }
#pragma unroll
        for (int j = 0; j < 16; ++j) {
            if ((j >> 2) == (i >> 2) && j != i)                // positives
                rloss += lg[j] - logf(expneg + expf(lg[j]));
        }
    }
    if (tid < 64) {
        rloss = rowsum16(rloss);   // lanes 0-15 hold row losses, others 0
        if (tid == 0) gloss[g] = rloss;
    }
}

__global__ void infonce_final_reduce(const float* __restrict__ gloss,
                                     float* __restrict__ out) {
    const int tid = threadIdx.x;
    float s = 0.f;
    for (int i = tid; i < NGROUP; i += 256) s += gloss[i];
    s += __shfl_xor(s, 1);
    s += __shfl_xor(s, 2);
    s += __shfl_xor(s, 4);
    s += __shfl_xor(s, 8);
    s += __shfl_xor(s, 16);
    s += __shfl_xor(s, 32);
    __shared__ float ws[4];
    const int lane = tid & 63, wid = tid >> 6;
    if (lane == 0) ws[wid] = s;
    __syncthreads();
    if (tid == 0) {
        const float t = ws[0] + ws[1] + ws[2] + ws[3];
        out[0] = -t / 48.0f;
    }
}

extern "C" void kernel_launch(void* const* d_in, const int* in_sizes, int n_in,
                              void* d_out, int out_size, void* d_ws, size_t ws_size,
                              hipStream_t stream) {
    const float4* feats = (const float4*)d_in[0];
    float* gloss = (float*)d_ws;   // 1024 floats scratch
    float* out   = (float*)d_out;  // 1 float

    infonce_group_kernel<<<NGROUP, 256, 0, stream>>>(feats, gloss);
    infonce_final_reduce<<<1, 256, 0, stream>>>(gloss, out);
}